// Round 2
// baseline (426.402 us; speedup 1.0000x reference)
//
#include <hip/hip_runtime.h>

// AttentionHead: B=8, N=2048, D=1024
// qkv = x @ W^T + b ; q,k,v split ; S = qk^T/32 ; P = softmax(S) ; out = P v
// Pipeline: cvt -> qkv_gemm -> transpose_v -> scores_gemm -> softmax -> pv_gemm
// Workspace layout (peak 230 MiB; bf16-S fallback peaks at 166 MiB):
//   [0,32MB)    x_bf   (reused later as V^T)
//   [32,38MB)   W_bf   (dead after qkv_gemm)
//   [38,70MB)   Q bf16
//   [70,102MB)  K bf16
//   [102,134MB) V bf16 (dead after transpose_v)
//   [102,230MB) S f32 rows, stride 2048 f32; P bf16 aliases rows (stride 4096 bf16)
//     fallback: [102,166MB) S bf16 rows stride 2048; softmax in-place

#define AS1 __attribute__((address_space(1)))
#define AS3 __attribute__((address_space(3)))

typedef __bf16 bfrag  __attribute__((ext_vector_type(8)));
typedef float  ffrag  __attribute__((ext_vector_type(4)));
typedef __bf16 bf16x4 __attribute__((ext_vector_type(4)));
typedef __bf16 bf16x8 __attribute__((ext_vector_type(8)));
typedef unsigned short ushort8v __attribute__((ext_vector_type(8)));

// ---------------- f32 -> bf16 convert, x4 vectorized ----------------
__global__ __launch_bounds__(256) void cvt_f32_bf16(const float* __restrict__ in,
                                                    __bf16* __restrict__ out, int n4) {
  int i = blockIdx.x * blockDim.x + threadIdx.x;
  int stride = gridDim.x * blockDim.x;
  for (; i < n4; i += stride) {
    float4 v = ((const float4*)in)[i];
    bf16x4 o;
    o[0] = (__bf16)v.x; o[1] = (__bf16)v.y; o[2] = (__bf16)v.z; o[3] = (__bf16)v.w;
    ((bf16x4*)out)[i] = o;
  }
}

// ---------------- B^T-form GEMM mainloop: C[m][o] = sum_k A[m][k]*B[o][k] ----
// 128x128 tile, BK=64, 256 threads (4 waves 2x2), mfma_f32_16x16x32_bf16.
// lds: [0,8192) = A tile [128][64], [8192,16384) = B tile [128][64]
__device__ __forceinline__ void gemm_bt_mainloop(
    const __bf16* __restrict__ A, const __bf16* __restrict__ B,
    int lda, int ldb, int K, __bf16* lds, ffrag acc[4][4]) {
  const int tid  = threadIdx.x;
  const int lane = tid & 63;
  const int w    = tid >> 6, wr = w >> 1, wc = w & 1;
  const int srow = lane >> 3;        // 0..7 within 8-row chunk
  const int scol = (lane & 7) * 8;   // element col, 8 bf16 = 16B per lane
  const int fr   = lane & 15;        // fragment row/col
  const int fk   = (lane >> 4) * 8;  // fragment k base
  __bf16* ldsA = lds;
  __bf16* ldsB = lds + 8192;

  for (int kt = 0; kt < K; kt += 64) {
    __syncthreads();  // previous iter's MFMAs done reading LDS
#pragma unroll
    for (int it = 0; it < 4; ++it) {
      int c   = it * 4 + w;          // 16 chunks of 1KB each (wave-uniform LDS base)
      int row = c * 8 + srow;
      const __bf16* ga = A + (size_t)row * lda + kt + scol;
      const __bf16* gb = B + (size_t)row * ldb + kt + scol;
      __builtin_amdgcn_global_load_lds((AS1 void*)ga, (AS3 void*)(ldsA + c * 512), 16, 0, 0);
      __builtin_amdgcn_global_load_lds((AS1 void*)gb, (AS3 void*)(ldsB + c * 512), 16, 0, 0);
    }
    __syncthreads();  // compiler inserts vmcnt(0) before barrier -> staging complete
#pragma unroll
    for (int ks = 0; ks < 2; ++ks) {
      bfrag a[4], b[4];
#pragma unroll
      for (int m = 0; m < 4; ++m)
        a[m] = *(const bfrag*)&ldsA[(wr * 64 + m * 16 + fr) * 64 + ks * 32 + fk];
#pragma unroll
      for (int n = 0; n < 4; ++n)
        b[n] = *(const bfrag*)&ldsB[(wc * 64 + n * 16 + fr) * 64 + ks * 32 + fk];
#pragma unroll
      for (int m = 0; m < 4; ++m)
#pragma unroll
        for (int n = 0; n < 4; ++n)
          acc[m][n] = __builtin_amdgcn_mfma_f32_16x16x32_bf16(a[m], b[n], acc[m][n], 0, 0, 0);
    }
  }
}

// ---------------- kernel 1: qkv projection ----------------
// A = x_bf [16384,1024], B = W_bf [3072,1024]; epilogue: +bias, q*=1/32, split.
__global__ __launch_bounds__(256) void qkv_gemm(
    const __bf16* __restrict__ Abf, const __bf16* __restrict__ Wbf,
    const float* __restrict__ bias,
    __bf16* __restrict__ Q, __bf16* __restrict__ Ko, __bf16* __restrict__ V) {
  __shared__ __bf16 lds[16384];
  ffrag acc[4][4];
#pragma unroll
  for (int m = 0; m < 4; ++m)
#pragma unroll
    for (int n = 0; n < 4; ++n) acc[m][n] = (ffrag)(0.0f);
  const int brow = blockIdx.x * 128, bcol = blockIdx.y * 128;
  gemm_bt_mainloop(Abf + (size_t)brow * 1024, Wbf + (size_t)bcol * 1024,
                   1024, 1024, 1024, lds, acc);
  const int lane = threadIdx.x & 63, w = threadIdx.x >> 6, wr = w >> 1, wc = w & 1;
#pragma unroll
  for (int m = 0; m < 4; ++m)
#pragma unroll
    for (int n = 0; n < 4; ++n) {
      int o = bcol + wc * 64 + n * 16 + (lane & 15);
      float bv = bias[o];
      float scale = (o < 1024) ? 0.03125f : 1.0f;  // fold 1/sqrt(1024) into Q
#pragma unroll
      for (int r = 0; r < 4; ++r) {
        int mg = brow + wr * 64 + m * 16 + (lane >> 4) * 4 + r;  // flat row = b*2048+n
        float val = (acc[m][n][r] + bv) * scale;
        size_t base = (size_t)mg * 1024;
        if (o < 1024)       Q[base + o]           = (__bf16)val;
        else if (o < 2048)  Ko[base + (o - 1024)] = (__bf16)val;
        else                V[base + (o - 2048)]  = (__bf16)val;
      }
    }
}

// ---------------- kernel 2: V [b][n][d] -> Vt [b][d][n] ----------------
__global__ __launch_bounds__(256) void transpose_v(const ushort* __restrict__ V,
                                                   ushort* __restrict__ Vt) {
  __shared__ ushort t[64][72];
  const int b = blockIdx.z;
  const int n0 = blockIdx.x * 64, d0 = blockIdx.y * 64;
  const int tid = threadIdx.x;
  const ushort* Vb = V + (size_t)b * 2048 * 1024;
  ushort* Vtb = Vt + (size_t)b * 1024 * 2048;
#pragma unroll
  for (int it = 0; it < 2; ++it) {
    int n = it * 32 + (tid >> 3);
    int d8 = (tid & 7) * 8;
    ushort8v v = *(const ushort8v*)&Vb[(size_t)(n0 + n) * 1024 + d0 + d8];
#pragma unroll
    for (int j = 0; j < 8; ++j) t[d8 + j][n] = v[j];
  }
  __syncthreads();
#pragma unroll
  for (int it = 0; it < 2; ++it) {
    int d = it * 32 + (tid >> 3);
    int n8 = (tid & 7) * 8;
    ushort8v v = *(const ushort8v*)&t[d][n8];
    *(ushort8v*)&Vtb[(size_t)(d0 + d) * 2048 + n0 + n8] = v;
  }
}

// ---------------- kernel 3: scores S = Q K^T (Q pre-scaled) ----------------
// ST = float (primary) or __bf16 (small-ws fallback)
template <typename ST>
__global__ __launch_bounds__(256) void scores_gemm(const __bf16* __restrict__ Q,
                                                   const __bf16* __restrict__ Kb,
                                                   ST* __restrict__ S) {
  __shared__ __bf16 lds[16384];
  ffrag acc[4][4];
#pragma unroll
  for (int m = 0; m < 4; ++m)
#pragma unroll
    for (int n = 0; n < 4; ++n) acc[m][n] = (ffrag)(0.0f);
  const int z = blockIdx.z;
  const int brow = blockIdx.x * 128, bcol = blockIdx.y * 128;
  gemm_bt_mainloop(Q + (size_t)z * 2048 * 1024 + (size_t)brow * 1024,
                   Kb + (size_t)z * 2048 * 1024 + (size_t)bcol * 1024,
                   1024, 1024, 1024, lds, acc);
  const int lane = threadIdx.x & 63, w = threadIdx.x >> 6, wr = w >> 1, wc = w & 1;
#pragma unroll
  for (int m = 0; m < 4; ++m)
#pragma unroll
    for (int n = 0; n < 4; ++n) {
      int o = bcol + wc * 64 + n * 16 + (lane & 15);
#pragma unroll
      for (int r = 0; r < 4; ++r) {
        int mg = brow + wr * 64 + m * 16 + (lane >> 4) * 4 + r;
        S[((size_t)(z * 2048 + mg)) * 2048 + o] = (ST)acc[m][n][r];
      }
    }
}

// ---------------- kernel 4a: row softmax, S f32 -> P bf16 (aliased rows) ----
// S row stride 2048 f32 (8KB slot); P row stride 4096 bf16 over the same memory.
// NOTE: no __restrict__ here — S and P intentionally alias.
__global__ __launch_bounds__(256) void softmax_f32(const float* S, __bf16* P) {
  const int row = blockIdx.x;
  const float* s = S + (size_t)row * 2048;
  __bf16* p = P + (size_t)row * 4096;
  const int t = threadIdx.x;
  float4 v0 = *(const float4*)&s[t * 4];
  float4 v1 = *(const float4*)&s[1024 + t * 4];
  float m = fmaxf(fmaxf(fmaxf(v0.x, v0.y), fmaxf(v0.z, v0.w)),
                  fmaxf(fmaxf(v1.x, v1.y), fmaxf(v1.z, v1.w)));
#pragma unroll
  for (int off = 32; off; off >>= 1) m = fmaxf(m, __shfl_xor(m, off, 64));
  __shared__ float redm[4];
  if ((t & 63) == 0) redm[t >> 6] = m;
  __syncthreads();
  m = fmaxf(fmaxf(redm[0], redm[1]), fmaxf(redm[2], redm[3]));
  float e[8];
  e[0] = __expf(v0.x - m); e[1] = __expf(v0.y - m);
  e[2] = __expf(v0.z - m); e[3] = __expf(v0.w - m);
  e[4] = __expf(v1.x - m); e[5] = __expf(v1.y - m);
  e[6] = __expf(v1.z - m); e[7] = __expf(v1.w - m);
  float sum = ((e[0] + e[1]) + (e[2] + e[3])) + ((e[4] + e[5]) + (e[6] + e[7]));
#pragma unroll
  for (int off = 32; off; off >>= 1) sum += __shfl_xor(sum, off, 64);
  __shared__ float reds[4];
  if ((t & 63) == 0) reds[t >> 6] = sum;
  __syncthreads();
  float inv = 1.0f / (((reds[0] + reds[1]) + (reds[2] + reds[3])));
  bf16x4 o0, o1;
#pragma unroll
  for (int j = 0; j < 4; ++j) { o0[j] = (__bf16)(e[j] * inv); o1[j] = (__bf16)(e[4 + j] * inv); }
  *(bf16x4*)&p[t * 4] = o0;
  *(bf16x4*)&p[1024 + t * 4] = o1;
}

// ---------------- kernel 4b: in-place bf16 softmax (fallback path) ----------
__global__ __launch_bounds__(256) void softmax_bf16(__bf16* S) {
  const int row = blockIdx.x;
  __bf16* s = S + (size_t)row * 2048;
  const int t = threadIdx.x;
  bf16x8 v = *(const bf16x8*)&s[t * 8];
  float f[8];
#pragma unroll
  for (int j = 0; j < 8; ++j) f[j] = (float)v[j];
  float m = fmaxf(fmaxf(fmaxf(f[0], f[1]), fmaxf(f[2], f[3])),
                  fmaxf(fmaxf(f[4], f[5]), fmaxf(f[6], f[7])));
#pragma unroll
  for (int off = 32; off; off >>= 1) m = fmaxf(m, __shfl_xor(m, off, 64));
  __shared__ float redm[4];
  if ((t & 63) == 0) redm[t >> 6] = m;
  __syncthreads();
  m = fmaxf(fmaxf(redm[0], redm[1]), fmaxf(redm[2], redm[3]));
  float e[8], sum = 0.f;
#pragma unroll
  for (int j = 0; j < 8; ++j) { e[j] = __expf(f[j] - m); sum += e[j]; }
#pragma unroll
  for (int off = 32; off; off >>= 1) sum += __shfl_xor(sum, off, 64);
  __shared__ float reds[4];
  if ((t & 63) == 0) reds[t >> 6] = sum;
  __syncthreads();
  float inv = 1.0f / (((reds[0] + reds[1]) + (reds[2] + reds[3])));
  bf16x8 o;
#pragma unroll
  for (int j = 0; j < 8; ++j) o[j] = (__bf16)(e[j] * inv);
  *(bf16x8*)&s[t * 8] = o;
}

// ---------------- kernel 5: out = P @ V  (via Vt, B^T form) ----------------
__global__ __launch_bounds__(256) void pv_gemm(const __bf16* __restrict__ P,
                                               const __bf16* __restrict__ Vt,
                                               float* __restrict__ O, int lda) {
  __shared__ __bf16 lds[16384];
  ffrag acc[4][4];
#pragma unroll
  for (int m = 0; m < 4; ++m)
#pragma unroll
    for (int n = 0; n < 4; ++n) acc[m][n] = (ffrag)(0.0f);
  const int z = blockIdx.z;
  const int brow = blockIdx.x * 128, bcol = blockIdx.y * 128;
  gemm_bt_mainloop(P + ((size_t)(z * 2048 + brow)) * lda,
                   Vt + (size_t)z * 1024 * 2048 + (size_t)bcol * 2048,
                   lda, 2048, 2048, lds, acc);
  const int lane = threadIdx.x & 63, w = threadIdx.x >> 6, wr = w >> 1, wc = w & 1;
#pragma unroll
  for (int m = 0; m < 4; ++m)
#pragma unroll
    for (int n = 0; n < 4; ++n) {
      int o = bcol + wc * 64 + n * 16 + (lane & 15);
#pragma unroll
      for (int r = 0; r < 4; ++r) {
        int mg = brow + wr * 64 + m * 16 + (lane >> 4) * 4 + r;
        O[((size_t)(z * 2048 + mg)) * 1024 + o] = acc[m][n][r];
      }
    }
}

extern "C" void kernel_launch(void* const* d_in, const int* in_sizes, int n_in,
                              void* d_out, int out_size, void* d_ws, size_t ws_size,
                              hipStream_t stream) {
  (void)in_sizes; (void)n_in; (void)out_size;
  const float* x    = (const float*)d_in[0];
  const float* W    = (const float*)d_in[1];
  const float* bias = (const float*)d_in[2];
  float* out = (float*)d_out;
  char* ws = (char*)d_ws;
  const size_t MB = 1u << 20;
  __bf16* x_bf = (__bf16*)(ws + 0);
  __bf16* W_bf = (__bf16*)(ws + 32 * MB);
  __bf16* Qb   = (__bf16*)(ws + 38 * MB);
  __bf16* Kb   = (__bf16*)(ws + 70 * MB);
  __bf16* Vb   = (__bf16*)(ws + 102 * MB);
  void*   Sbase = (void*)(ws + 102 * MB);    // overwrites V after transpose_v
  __bf16* Vt   = (__bf16*)(ws + 0);          // reuses x_bf after qkv_gemm

  // 1-2. convert inputs to bf16
  cvt_f32_bf16<<<2048, 256, 0, stream>>>(x, x_bf, 16777216 / 4);
  cvt_f32_bf16<<<1024, 256, 0, stream>>>(W, W_bf, 3145728 / 4);
  // 3. qkv projection (+bias, q scaled by 1/32)
  qkv_gemm<<<dim3(128, 24, 1), 256, 0, stream>>>(x_bf, W_bf, bias, Qb, Kb, Vb);
  // 4. transpose V -> Vt (into old x_bf region)
  transpose_v<<<dim3(32, 16, 8), 256, 0, stream>>>((const ushort*)Vb, (ushort*)Vt);

  if (ws_size >= 230 * MB) {
    // primary: f32 scores at [102,230) MiB, P bf16 aliases rows
    float*  S = (float*)Sbase;
    __bf16* P = (__bf16*)Sbase;
    scores_gemm<float><<<dim3(16, 16, 8), 256, 0, stream>>>(Qb, Kb, S);
    softmax_f32<<<16384, 256, 0, stream>>>(S, P);
    pv_gemm<<<dim3(16, 8, 8), 256, 0, stream>>>(P, Vt, out, 4096);
  } else {
    // fallback: bf16 scores at [102,166) MiB, in-place softmax
    __bf16* S = (__bf16*)Sbase;
    scores_gemm<__bf16><<<dim3(16, 16, 8), 256, 0, stream>>>(Qb, Kb, S);
    softmax_bf16<<<16384, 256, 0, stream>>>(S);
    pv_gemm<<<dim3(16, 8, 8), 256, 0, stream>>>(S, Vt, out, 2048);
  }
}

// Round 4
// 327.805 us; speedup vs baseline: 1.3008x; 1.3008x over previous
//
#include <hip/hip_runtime.h>

// AttentionHead: B=8, N=2048, D=1024
// qkv = x @ W^T + b ; q,k,v split ; S = qk^T/32 ; P = softmax(S) ; out = P v
// GEMMs: 256x256 8-phase schedule, REGION-STAGGERED staging (race-free by design):
//   per-wave work spans both halves of A and B; phase p reads quadrant (qa,qb);
//   each stage targets a region fully retired at the previous phase's end barrier.
//   vmcnt: P1=6, P4=8, P5=6, P8=8 (pipeline never drains; 3-5 halves in flight).
// Workspace layout (peak 230 MiB; bf16-S fallback peaks at 166 MiB):
//   [0,32MB)    x_bf   (reused later as V^T)
//   [32,38MB)   W_bf   (dead after qkv)
//   [38,70MB)   Q bf16
//   [70,102MB)  K bf16
//   [102,134MB) V bf16 (dead after transpose_v)
//   [102,230MB) S f32 rows stride 2048 f32; P bf16 aliases rows (stride 4096 bf16)

#define AS1 __attribute__((address_space(1)))
#define AS3 __attribute__((address_space(3)))

typedef __bf16 bfrag  __attribute__((ext_vector_type(8)));
typedef float  ffrag  __attribute__((ext_vector_type(4)));
typedef __bf16 bf16x4 __attribute__((ext_vector_type(4)));
typedef __bf16 bf16x8 __attribute__((ext_vector_type(8)));
typedef unsigned short ushort8v __attribute__((ext_vector_type(8)));

// ---------------- f32 -> bf16 convert, x4 vectorized ----------------
__global__ __launch_bounds__(256) void cvt_f32_bf16(const float* __restrict__ in,
                                                    __bf16* __restrict__ out, int n4) {
  int i = blockIdx.x * blockDim.x + threadIdx.x;
  int stride = gridDim.x * blockDim.x;
  for (; i < n4; i += stride) {
    float4 v = ((const float4*)in)[i];
    bf16x4 o;
    o[0] = (__bf16)v.x; o[1] = (__bf16)v.y; o[2] = (__bf16)v.z; o[3] = (__bf16)v.w;
    ((bf16x4*)out)[i] = o;
  }
}

// =================== 256x256 8-phase GEMM mainloop ===================
// C[m][o] = sum_k A[m][k] * B[o][k]   (both operands K-major, B^T form)
// 512 threads = 8 waves (wr = wid>>2 in {0,1}, wc = wid&3 in {0..3}).
// LDS 128 KiB: buf{0,1} x (A[256][64] | B[256][64]) bf16, tile t -> buf t&1.
// Half-regions (8 KiB each): h0=A rows 0-127, h1=A rows 128-255, h2=B rows
// 0-127, h3=B rows 128-255 at offset h*8192 elems within the buffer.
// Swizzle: LDS[r][c] = G[r][c ^ ((r&7)<<3)] (16B-granular XOR), applied by
// pre-swizzling the global SOURCE col; global_load_lds dest stays linear.
// Phase p computes quadrant (qa,qb); A rows qa*128+wr*64+..., B rows
// qb*128+wc*32+... so buf0 regions retire: A0@P2, B0@P3, A1,B1@P4 (buf1: +4).
// Stage slots (issue-after-retire, verified): P1:A1(t+1) P2:B1(t+1) P3:A0(t+2)
// P4:B0(t+2) P5:A1(t+2) P6:B1(t+2) P7:A0(t+3) P8:B0(t+3).
// Out-of-range tail tiles wrap to t-2 = byte-identical rewrite (safe).

__device__ __forceinline__ void stage_half(
    const __bf16* __restrict__ Atile, const __bf16* __restrict__ Btile,
    int lda, int ldb, int nT, __bf16* lds, int tid, int t, int h) {
  const int te = (t < nT) ? t : (t - 2);   // same parity -> same buffer, same data
  const int kt = te * 64;
  const __bf16* src = (h < 2) ? Atile : Btile;
  const int ld = (h < 2) ? lda : ldb;
  const int row0 = (h & 1) * 128;
  __bf16* dst = lds + (te & 1) * 32768 + h * 8192;
#pragma unroll
  for (int l = 0; l < 2; ++l) {
    const int y = l * 4096 + tid * 8;                  // linear LDS dest (uniform base + lane*16B)
    const int r = y >> 6;                              // row within half (0..127)
    const int c = ((tid & 7) * 8) ^ ((r & 7) << 3);    // inverse-swizzled source col
    __builtin_amdgcn_global_load_lds((AS1 void*)(src + (size_t)(row0 + r) * ld + kt + c),
                                     (AS3 void*)(dst + y), 16, 0, 0);
  }
}

template <int QA, int QB>
__device__ __forceinline__ void rd_frags(const __bf16* lds, int bufoff,
                                         int aRowBase, int bRowBase, int ck0, int ck1,
                                         bfrag a[4][2], bfrag b[2][2]) {
#pragma unroll
  for (int m = 0; m < 4; ++m) {
    a[m][0] = *(const bfrag*)&lds[bufoff + aRowBase + QA * 8192 + m * 1024 + ck0];
    a[m][1] = *(const bfrag*)&lds[bufoff + aRowBase + QA * 8192 + m * 1024 + ck1];
  }
#pragma unroll
  for (int n = 0; n < 2; ++n) {
    b[n][0] = *(const bfrag*)&lds[bufoff + bRowBase + QB * 8192 + n * 1024 + ck0];
    b[n][1] = *(const bfrag*)&lds[bufoff + bRowBase + QB * 8192 + n * 1024 + ck1];
  }
}

template <int QA, int QB>
__device__ __forceinline__ void mfma_q(const bfrag a[4][2], const bfrag b[2][2],
                                       ffrag acc[8][4]) {
#pragma unroll
  for (int m = 0; m < 4; ++m)
#pragma unroll
    for (int n = 0; n < 2; ++n)
#pragma unroll
      for (int ks = 0; ks < 2; ++ks)
        acc[QA * 4 + m][QB * 2 + n] = __builtin_amdgcn_mfma_f32_16x16x32_bf16(
            a[m][ks], b[n][ks], acc[QA * 4 + m][QB * 2 + n], 0, 0, 0);
}

#define PHASE(BUF, QA, QB, ST_T, ST_H, VMC)                                    \
  {                                                                            \
    bfrag a[4][2], b[2][2];                                                    \
    rd_frags<QA, QB>(lds, (BUF) * 32768, aRowBase, bRowBase, ck0, ck1, a, b);  \
    stage_half(Atile, Btile, lda, ldb, nT, lds, tid, (ST_T), (ST_H));          \
    if ((VMC) == 6) asm volatile("s_waitcnt vmcnt(6)" ::: "memory");           \
    if ((VMC) == 8) asm volatile("s_waitcnt vmcnt(8)" ::: "memory");           \
    __builtin_amdgcn_sched_barrier(0);                                         \
    __builtin_amdgcn_s_barrier();                                              \
    asm volatile("s_waitcnt lgkmcnt(0)" ::: "memory");                         \
    __builtin_amdgcn_sched_barrier(0);                                         \
    __builtin_amdgcn_s_setprio(1);                                             \
    mfma_q<QA, QB>(a, b, acc);                                                 \
    __builtin_amdgcn_s_setprio(0);                                             \
    __builtin_amdgcn_sched_barrier(0);                                         \
    __builtin_amdgcn_s_barrier();                                              \
    __builtin_amdgcn_sched_barrier(0);                                         \
  }

__device__ __forceinline__ void gemm256_mainloop(
    const __bf16* __restrict__ Atile, const __bf16* __restrict__ Btile,
    int lda, int ldb, int K, __bf16* lds, ffrag acc[8][4]) {
  const int tid  = threadIdx.x;
  const int lane = tid & 63;
  const int wid  = tid >> 6;
  const int wr   = wid >> 2, wc = wid & 3;
  const int fr   = lane & 15;
  const int fk   = (lane >> 4) * 8;
  const int swz  = (fr & 7) << 3;
  const int ck0  = fk ^ swz;            // ks=0 frag col (swizzled)
  const int ck1  = (32 + fk) ^ swz;     // ks=1
  const int aRowBase = (wr * 64 + fr) * 64;
  const int bRowBase = 16384 + (wc * 32 + fr) * 64;
  const int nT = K >> 6;

  // prologue issue order: A0,B0,A1,B1 of T0; A0,B0 of T1.
  // vmcnt(8) -> A0,B0 of T0 complete (P1's reads); 4 halves in flight.
  stage_half(Atile, Btile, lda, ldb, nT, lds, tid, 0, 0);
  stage_half(Atile, Btile, lda, ldb, nT, lds, tid, 0, 2);
  stage_half(Atile, Btile, lda, ldb, nT, lds, tid, 0, 1);
  stage_half(Atile, Btile, lda, ldb, nT, lds, tid, 0, 3);
  stage_half(Atile, Btile, lda, ldb, nT, lds, tid, 1, 0);
  stage_half(Atile, Btile, lda, ldb, nT, lds, tid, 1, 2);
  asm volatile("s_waitcnt vmcnt(8)" ::: "memory");
  __builtin_amdgcn_s_barrier();

  const int nIter = nT >> 1;
#pragma unroll 1
  for (int i = 0; i < nIter; ++i) {
    const int t1 = 2 * i + 1, t2 = 2 * i + 2, t3 = 2 * i + 3;
    PHASE(0, 0, 0, t1, 1, 6);   // read T2i quad(A0,B0); stage A1(T2i+1); wait->A1,B1(T2i) done
    PHASE(0, 0, 1, t1, 3, 0);   // read (A0,B1); stage B1(T2i+1)
    PHASE(0, 1, 0, t2, 0, 0);   // read (A1,B0); stage A0(T2i+2)
    PHASE(0, 1, 1, t2, 2, 8);   // read (A1,B1); stage B0(T2i+2); wait->A0,B0(T2i+1) done
    PHASE(1, 0, 0, t2, 1, 6);   // read T2i+1 (A0,B0); stage A1(T2i+2); wait->A1,B1(T2i+1) done
    PHASE(1, 0, 1, t2, 3, 0);   // read (A0,B1); stage B1(T2i+2)
    PHASE(1, 1, 0, t3, 0, 0);   // read (A1,B0); stage A0(T2i+3)
    PHASE(1, 1, 1, t3, 2, 8);   // read (A1,B1); stage B0(T2i+3); wait->A0,B0(T2i+2) done
  }
}

#define ACC_ZERO()                                                             \
  ffrag acc[8][4];                                                             \
  _Pragma("unroll") for (int m = 0; m < 8; ++m)                                \
  _Pragma("unroll") for (int n = 0; n < 4; ++n) acc[m][n] = (ffrag)(0.0f);

// Epilogue mapping for acc[i][j]: qa=i>>2, m=i&3, qb=j>>1, n=j&1.
// row = brow + qa*128 + wr*64 + m*16 + (lane>>4)*4 + r
// col = bcol + qb*128 + wc*32 + n*16 + (lane&15)

// ---------------- kernel 1: qkv projection ----------------
__global__ __launch_bounds__(512, 2) void qkv_gemm256(
    const __bf16* __restrict__ Abf, const __bf16* __restrict__ Wbf,
    const float* __restrict__ bias,
    __bf16* __restrict__ Q, __bf16* __restrict__ Ko, __bf16* __restrict__ V) {
  __shared__ __bf16 lds[65536];
  ACC_ZERO();
  int bid = (int)blockIdx.x;
  bid = (bid & 7) * 96 + (bid >> 3);          // XCD swizzle (768 % 8 == 0, bijective)
  const int brow = (bid / 12) * 256;
  const int bcol = (bid % 12) * 256;
  gemm256_mainloop(Abf + (size_t)brow * 1024, Wbf + (size_t)bcol * 1024,
                   1024, 1024, 1024, lds, acc);
  const int lane = threadIdx.x & 63, wid = threadIdx.x >> 6;
  const int wr = wid >> 2, wc = wid & 3;
  const int region = bcol >> 10;              // 0=Q,1=K,2=V (tile within one region)
  __bf16* dst = region == 0 ? Q : (region == 1 ? Ko : V);
  const float scale = region == 0 ? 0.03125f : 1.0f;   // fold 1/sqrt(1024) into Q
#pragma unroll
  for (int j = 0; j < 4; ++j) {
    const int qb = j >> 1, n = j & 1;
    const int col = bcol + qb * 128 + wc * 32 + n * 16 + (lane & 15);
    const int o = col & 1023;
    const float bv = bias[col];
#pragma unroll
    for (int i = 0; i < 8; ++i) {
      const int qa = i >> 2, m = i & 3;
#pragma unroll
      for (int r = 0; r < 4; ++r) {
        const int mg = brow + qa * 128 + wr * 64 + m * 16 + (lane >> 4) * 4 + r;
        dst[(size_t)mg * 1024 + o] = (__bf16)((acc[i][j][r] + bv) * scale);
      }
    }
  }
}

// ---------------- kernel 2: V [b][n][d] -> Vt [b][d][n] ----------------
__global__ __launch_bounds__(256) void transpose_v(const ushort* __restrict__ V,
                                                   ushort* __restrict__ Vt) {
  __shared__ ushort t[64][72];
  const int b = blockIdx.z;
  const int n0 = blockIdx.x * 64, d0 = blockIdx.y * 64;
  const int tid = threadIdx.x;
  const ushort* Vb = V + (size_t)b * 2048 * 1024;
  ushort* Vtb = Vt + (size_t)b * 1024 * 2048;
#pragma unroll
  for (int it = 0; it < 2; ++it) {
    int n = it * 32 + (tid >> 3);
    int d8 = (tid & 7) * 8;
    ushort8v v = *(const ushort8v*)&Vb[(size_t)(n0 + n) * 1024 + d0 + d8];
#pragma unroll
    for (int j = 0; j < 8; ++j) t[d8 + j][n] = v[j];
  }
  __syncthreads();
#pragma unroll
  for (int it = 0; it < 2; ++it) {
    int d = it * 32 + (tid >> 3);
    int n8 = (tid & 7) * 8;
    ushort8v v = *(const ushort8v*)&t[d][n8];
    *(ushort8v*)&Vtb[(size_t)(d0 + d) * 2048 + n0 + n8] = v;
  }
}

// ---------------- kernel 3: scores S = Q K^T (Q pre-scaled) ----------------
template <typename ST>
__global__ __launch_bounds__(512, 2) void scores_gemm256(const __bf16* __restrict__ Q,
                                                         const __bf16* __restrict__ Kb,
                                                         ST* __restrict__ S) {
  __shared__ __bf16 lds[65536];
  ACC_ZERO();
  const int z = blockIdx.z;
  const int brow = blockIdx.x * 256, bcol = blockIdx.y * 256;
  gemm256_mainloop(Q + (size_t)z * 2048 * 1024 + (size_t)brow * 1024,
                   Kb + (size_t)z * 2048 * 1024 + (size_t)bcol * 1024,
                   1024, 1024, 1024, lds, acc);
  const int lane = threadIdx.x & 63, wid = threadIdx.x >> 6;
  const int wr = wid >> 2, wc = wid & 3;
#pragma unroll
  for (int j = 0; j < 4; ++j) {
    const int qb = j >> 1, n = j & 1;
    const int o = bcol + qb * 128 + wc * 32 + n * 16 + (lane & 15);
#pragma unroll
    for (int i = 0; i < 8; ++i) {
      const int qa = i >> 2, m = i & 3;
#pragma unroll
      for (int r = 0; r < 4; ++r) {
        const int mg = brow + qa * 128 + wr * 64 + m * 16 + (lane >> 4) * 4 + r;
        S[((size_t)(z * 2048 + mg)) * 2048 + o] = (ST)acc[i][j][r];
      }
    }
  }
}

// ---------------- kernel 4a: row softmax, S f32 -> P bf16 (aliased rows) ----
__global__ __launch_bounds__(256) void softmax_f32(const float* S, __bf16* P) {
  const int row = blockIdx.x;
  const float* s = S + (size_t)row * 2048;
  __bf16* p = P + (size_t)row * 4096;
  const int t = threadIdx.x;
  float4 v0 = *(const float4*)&s[t * 4];
  float4 v1 = *(const float4*)&s[1024 + t * 4];
  float m = fmaxf(fmaxf(fmaxf(v0.x, v0.y), fmaxf(v0.z, v0.w)),
                  fmaxf(fmaxf(v1.x, v1.y), fmaxf(v1.z, v1.w)));
#pragma unroll
  for (int off = 32; off; off >>= 1) m = fmaxf(m, __shfl_xor(m, off, 64));
  __shared__ float redm[4];
  if ((t & 63) == 0) redm[t >> 6] = m;
  __syncthreads();
  m = fmaxf(fmaxf(redm[0], redm[1]), fmaxf(redm[2], redm[3]));
  float e[8];
  e[0] = __expf(v0.x - m); e[1] = __expf(v0.y - m);
  e[2] = __expf(v0.z - m); e[3] = __expf(v0.w - m);
  e[4] = __expf(v1.x - m); e[5] = __expf(v1.y - m);
  e[6] = __expf(v1.z - m); e[7] = __expf(v1.w - m);
  float sum = ((e[0] + e[1]) + (e[2] + e[3])) + ((e[4] + e[5]) + (e[6] + e[7]));
#pragma unroll
  for (int off = 32; off; off >>= 1) sum += __shfl_xor(sum, off, 64);
  __shared__ float reds[4];
  if ((t & 63) == 0) reds[t >> 6] = sum;
  __syncthreads();
  float inv = 1.0f / (((reds[0] + reds[1]) + (reds[2] + reds[3])));
  bf16x4 o0, o1;
#pragma unroll
  for (int j = 0; j < 4; ++j) { o0[j] = (__bf16)(e[j] * inv); o1[j] = (__bf16)(e[4 + j] * inv); }
  *(bf16x4*)&p[t * 4] = o0;
  *(bf16x4*)&p[1024 + t * 4] = o1;
}

// ---------------- kernel 4b: in-place bf16 softmax (fallback path) ----------
__global__ __launch_bounds__(256) void softmax_bf16(__bf16* S) {
  const int row = blockIdx.x;
  __bf16* s = S + (size_t)row * 2048;
  const int t = threadIdx.x;
  bf16x8 v = *(const bf16x8*)&s[t * 8];
  float f[8];
#pragma unroll
  for (int j = 0; j < 8; ++j) f[j] = (float)v[j];
  float m = fmaxf(fmaxf(fmaxf(f[0], f[1]), fmaxf(f[2], f[3])),
                  fmaxf(fmaxf(f[4], f[5]), fmaxf(f[6], f[7])));
#pragma unroll
  for (int off = 32; off; off >>= 1) m = fmaxf(m, __shfl_xor(m, off, 64));
  __shared__ float redm[4];
  if ((t & 63) == 0) redm[t >> 6] = m;
  __syncthreads();
  m = fmaxf(fmaxf(redm[0], redm[1]), fmaxf(redm[2], redm[3]));
  float e[8], sum = 0.f;
#pragma unroll
  for (int j = 0; j < 8; ++j) { e[j] = __expf(f[j] - m); sum += e[j]; }
#pragma unroll
  for (int off = 32; off; off >>= 1) sum += __shfl_xor(sum, off, 64);
  __shared__ float reds[4];
  if ((t & 63) == 0) reds[t >> 6] = sum;
  __syncthreads();
  float inv = 1.0f / (((reds[0] + reds[1]) + (reds[2] + reds[3])));
  bf16x8 o;
#pragma unroll
  for (int j = 0; j < 8; ++j) o[j] = (__bf16)(e[j] * inv);
  *(bf16x8*)&s[t * 8] = o;
}

// ---------------- kernel 5: out = P @ V  (via Vt, B^T form) ----------------
__global__ __launch_bounds__(512, 2) void pv_gemm256(const __bf16* __restrict__ P,
                                                     const __bf16* __restrict__ Vt,
                                                     float* __restrict__ O, int lda) {
  __shared__ __bf16 lds[65536];
  ACC_ZERO();
  const int z = blockIdx.z;
  const int brow = blockIdx.x * 256, bcol = blockIdx.y * 256;
  gemm256_mainloop(P + (size_t)(z * 2048 + brow) * lda,
                   Vt + (size_t)z * 1024 * 2048 + (size_t)bcol * 2048,
                   lda, 2048, 2048, lds, acc);
  const int lane = threadIdx.x & 63, wid = threadIdx.x >> 6;
  const int wr = wid >> 2, wc = wid & 3;
#pragma unroll
  for (int j = 0; j < 4; ++j) {
    const int qb = j >> 1, n = j & 1;
    const int o = bcol + qb * 128 + wc * 32 + n * 16 + (lane & 15);
#pragma unroll
    for (int i = 0; i < 8; ++i) {
      const int qa = i >> 2, m = i & 3;
#pragma unroll
      for (int r = 0; r < 4; ++r) {
        const int mg = brow + qa * 128 + wr * 64 + m * 16 + (lane >> 4) * 4 + r;
        O[((size_t)(z * 2048 + mg)) * 1024 + o] = acc[i][j][r];
      }
    }
  }
}

extern "C" void kernel_launch(void* const* d_in, const int* in_sizes, int n_in,
                              void* d_out, int out_size, void* d_ws, size_t ws_size,
                              hipStream_t stream) {
  (void)in_sizes; (void)n_in; (void)out_size;
  const float* x    = (const float*)d_in[0];
  const float* W    = (const float*)d_in[1];
  const float* bias = (const float*)d_in[2];
  float* out = (float*)d_out;
  char* ws = (char*)d_ws;
  const size_t MB = 1u << 20;
  __bf16* x_bf = (__bf16*)(ws + 0);
  __bf16* W_bf = (__bf16*)(ws + 32 * MB);
  __bf16* Qb   = (__bf16*)(ws + 38 * MB);
  __bf16* Kb   = (__bf16*)(ws + 70 * MB);
  __bf16* Vb   = (__bf16*)(ws + 102 * MB);
  void*   Sbase = (void*)(ws + 102 * MB);    // overwrites V after transpose_v
  __bf16* Vt   = (__bf16*)(ws + 0);          // reuses x_bf after qkv_gemm

  cvt_f32_bf16<<<2048, 256, 0, stream>>>(x, x_bf, 16777216 / 4);
  cvt_f32_bf16<<<1024, 256, 0, stream>>>(W, W_bf, 3145728 / 4);
  qkv_gemm256<<<768, 512, 0, stream>>>(x_bf, W_bf, bias, Qb, Kb, Vb);
  transpose_v<<<dim3(32, 16, 8), 256, 0, stream>>>((const ushort*)Vb, (ushort*)Vt);

  if (ws_size >= 230 * MB) {
    float*  S = (float*)Sbase;
    __bf16* P = (__bf16*)Sbase;
    scores_gemm256<float><<<dim3(8, 8, 8), 512, 0, stream>>>(Qb, Kb, S);
    softmax_f32<<<16384, 256, 0, stream>>>(S, P);
    pv_gemm256<<<dim3(8, 4, 8), 512, 0, stream>>>(P, Vt, out, 4096);
  } else {
    __bf16* S = (__bf16*)Sbase;
    scores_gemm256<__bf16><<<dim3(8, 8, 8), 512, 0, stream>>>(Qb, Kb, S);
    softmax_bf16<<<16384, 256, 0, stream>>>(S);
    pv_gemm256<<<dim3(8, 4, 8), 512, 0, stream>>>(S, Vt, out, 2048);
  }
}